// Round 11
// baseline (302.702 us; speedup 1.0000x reference)
//
#include <hip/hip_runtime.h>
#include <hip/hip_bf16.h>
#include <math.h>

typedef __attribute__((ext_vector_type(4))) float  float4v;
typedef __attribute__((ext_vector_type(2))) float  float2v;
typedef __attribute__((ext_vector_type(8))) short  short8;
typedef __attribute__((ext_vector_type(4))) int    int4v;

#define B_ 8
#define L_ 384
#define H_ 128

__device__ __forceinline__ float bflo(unsigned int u){ unsigned int t = u << 16; float f; __builtin_memcpy(&f,&t,4); return f; }
__device__ __forceinline__ unsigned short f2bf(float f){
  unsigned int t; __builtin_memcpy(&t,&f,4);
  return (unsigned short)((t + 0x7fffu + ((t>>16)&1u)) >> 16);
}
__device__ __forceinline__ float fsig(float x){ return __fdividef(1.f, 1.f + __expf(-x)); }

// lgkm-only barrier: LDS ordering without draining in-flight global loads/stores
__device__ __forceinline__ void barrier_lds(){
  asm volatile("s_waitcnt lgkmcnt(0)\n\ts_barrier" ::: "memory");
}

// ---------------- MFMA row-GEMM ----------------
// act==0: linear. act==3: gate-interleaved scatter. act==4: exp2(C2*val).
template<int K>
__device__ __forceinline__ void mfma_rowgemm_body(
    unsigned short* in_s,
    const float* __restrict__ inA,
    const float* __restrict__ W, const float* __restrict__ bias,
    const float* __restrict__ bias2, float* __restrict__ out,
    int Ntotal, int act, int row0, int ob)
{
  constexpr int KP = K + 2;
  const int tid  = threadIdx.x;
  const int w    = tid >> 6;
  const int l    = tid & 63;
  const int c    = l & 15;
  const int quad = l >> 4;

  #pragma unroll
  for (int it = 0; it < K/32; ++it) {
    int idx = it*256 + tid;
    int r = idx / (K/4);
    int k = (idx % (K/4)) * 4;
    float4v f = *(const float4v*)(inA + (size_t)(row0+r)*K + k);
    unsigned int p0 = (unsigned int)f2bf(f.x) | ((unsigned int)f2bf(f.y) << 16);
    unsigned int p1 = (unsigned int)f2bf(f.z) | ((unsigned int)f2bf(f.w) << 16);
    *(unsigned int*)&in_s[r*KP + k]     = p0;
    *(unsigned int*)&in_s[r*KP + k + 2] = p1;
  }

  const int n = ob + w*16 + c;
  short8 bfr[K/32];
  #pragma unroll
  for (int kt = 0; kt < K/32; ++kt) {
    const float* src = W + (size_t)n*K + kt*32 + quad*8;
    float4v f0 = *(const float4v*)(src);
    float4v f1 = *(const float4v*)(src + 4);
    short8 v;
    v[0]=(short)f2bf(f0[0]); v[1]=(short)f2bf(f0[1]); v[2]=(short)f2bf(f0[2]); v[3]=(short)f2bf(f0[3]);
    v[4]=(short)f2bf(f1[0]); v[5]=(short)f2bf(f1[1]); v[6]=(short)f2bf(f1[2]); v[7]=(short)f2bf(f1[3]);
    bfr[kt] = v;
  }
  __syncthreads();

  const float4v z4 = {0.f,0.f,0.f,0.f};
  float4v acc0 = z4, acc1 = z4;
  #pragma unroll
  for (int kt = 0; kt < K/32; ++kt) {
    short8 a0 = *(const short8*)&in_s[(c     )*KP + kt*32 + quad*8];
    short8 a1 = *(const short8*)&in_s[(16 + c)*KP + kt*32 + quad*8];
    acc0 = __builtin_amdgcn_mfma_f32_16x16x32_bf16(a0, bfr[kt], acc0, 0,0,0);
    acc1 = __builtin_amdgcn_mfma_f32_16x16x32_bf16(a1, bfr[kt], acc1, 0,0,0);
  }

  const float C2 = 2.8853900817779268f;   // 2*log2(e)
  float bv = bias[n] + (bias2 ? bias2[n] : 0.f);
  #pragma unroll
  for (int mt = 0; mt < 2; ++mt) {
    float4v A = mt ? acc1 : acc0;
    #pragma unroll
    for (int r = 0; r < 4; ++r) {
      int m = mt*16 + quad*4 + r;
      float val = A[r] + bv;
      if (act == 4)
        val = __builtin_amdgcn_exp2f(C2 * val);
      if (act == 3)
        out[(size_t)(row0+m)*Ntotal + (n & 127)*4 + (n >> 7)] = val;
      else
        out[(size_t)(row0+m)*Ntotal + n] = val;
    }
  }
}

// Projections emit Ex = exp2(C2*x_proj), Ey = exp2(C2*y_proj2)
__global__ __launch_bounds__(256) void proj_mfma_kernel(
    const float* __restrict__ x, const float* __restrict__ y,
    const float* __restrict__ Wup_w, const float* __restrict__ Wup_b,
    const float* __restrict__ Wq_w, const float* __restrict__ Wq_b,
    const float* __restrict__ Wvp_b,
    float* __restrict__ xp, float* __restrict__ yp)
{
  __shared__ __align__(16) unsigned short in_s[32*130];
  int bx = blockIdx.x;
  if (bx < 192)
    mfma_rowgemm_body<128>(in_s, x, Wup_w, Wup_b, nullptr,
                           xp, 128, 4, (bx>>1)*32, (bx&1)*64);
  else {
    bx -= 192;
    mfma_rowgemm_body<128>(in_s, y, Wq_w, Wq_b, Wvp_b,
                           yp, 128, 4, (bx>>1)*32, (bx&1)*64);
  }
}

// Fused additive attention, R23: each lane computes TWO scores per c-iter
// (j = u and u+32) from a 64-row yp_s tile. Per k-4 step: 4 LDS b128 reads
// (yv0,yv1,xv,vv) feed 2 scores -> 2 reads/score vs 3 (score loop is the
// dominant LDS-pipe term; R21/R22 showed attn is throughput-bound there).
// c-iters 6 -> 3, barriers halved. PV: two MFMA K=32 chunks per c-iter
// (pf0/pf1 x yb half0/half1), one rescale per c-iter. Same grid/ctp/ml.
__global__ __launch_bounds__(256) void attn_kernel(
    const float* __restrict__ xp, const float* __restrict__ yp,
    const float* __restrict__ y, const unsigned char* __restrict__ xmask,
    const unsigned char* __restrict__ ymask, const float* __restrict__ Vw,
    const float* __restrict__ Vb,
    float* __restrict__ ctpbase, float* __restrict__ ml)
{
  __shared__ __align__(16) float xp_s[8][128];
  __shared__ __align__(16) float v2_s[128];
  __shared__ __align__(16) float yp_s[64][132];
  __shared__ __align__(16) unsigned short p_s0[16][40];  // bf16 A-frag j-half0
  __shared__ __align__(16) unsigned short p_s1[16][40];  // bf16 A-frag j-half1
  __shared__ float sc_s[16];
  __shared__ float xm_s[8];
  __shared__ float ym_s[64];
  __shared__ float sv_s;
  const int tid = threadIdx.x;
  const int b   = blockIdx.y;
  const int t0  = blockIdx.x * 8;
  const int jh  = blockIdx.z;      // 2 splits x 192 j
  const int jb  = jh * 192;
  const int w    = tid >> 6;       // wave
  const int l    = tid & 63;
  const int c16  = l & 15;
  const int quad = l >> 4;
  {
    int r = tid >> 5, k4 = (tid & 31) * 4;
    float4v f = *(const float4v*)(xp + ((size_t)(b*L_ + t0 + r))*H_ + k4);
    *(float4v*)&xp_s[r][k4] = f;
    if (tid < 32) {
      float4v v = *(const float4v*)(Vw + tid*4);
      float4v v2; v2[0]=2.f*v[0]; v2[1]=2.f*v[1]; v2[2]=2.f*v[2]; v2[3]=2.f*v[3];
      *(float4v*)&v2_s[tid*4] = v2;
    }
    if (tid < 8) xm_s[tid] = xmask[b*L_ + t0 + tid] ? 0.f : 1.f;
    if (tid < 16) sc_s[tid] = 0.f;
    for (int i = 320 + tid; i < 640; i += 256) {
      ((unsigned short*)p_s0)[i] = 0;
      ((unsigned short*)p_s1)[i] = 0;
    }
  }
  __syncthreads();
  if (tid < 32) {
    float4v v = *(const float4v*)&v2_s[tid*4];
    float sm = (v[0]+v[1]) + (v[2]+v[3]);
    #pragma unroll
    for (int off = 16; off >= 1; off >>= 1) sm += __shfl_xor(sm, off);
    if (tid == 0) sv_s = 0.5f*sm + Vb[0];
  }

  float4v rp[8];
  unsigned char ymb = 0;
  {
    #pragma unroll
    for (int it = 0; it < 8; ++it) {
      int idx = it*256 + tid; int r = idx >> 5; int k4 = (idx & 31) * 4;
      rp[it] = *(const float4v*)(yp + ((size_t)(b*L_ + jb + r))*H_ + k4);
    }
    if (tid < 64) ymb = ymask[b*L_ + jb + tid];
  }

  const int t = tid >> 5, u = tid & 31;
  float mrun = -__builtin_inff(), lrun = 0.f;
  const float4v z4 = {0.f,0.f,0.f,0.f};
  float4v acc0 = z4, acc1 = z4;    // ct C-regs: ntiles w and w+4
  float svc = 0.f, xmv = 0.f;

  for (int c = 0; c < 3; ++c) {
    __syncthreads();
    #pragma unroll
    for (int it = 0; it < 8; ++it) {
      int idx = it*256 + tid; int r = idx >> 5; int k4 = (idx & 31) * 4;
      *(float4v*)&yp_s[r][k4] = rp[it];
    }
    if (tid < 64) ym_s[tid] = ymb ? 0.f : 1.f;
    __syncthreads();
    if (c == 0) { svc = sv_s; xmv = xm_s[t]; }
    short8 yb00, yb10, yb01, yb11;   // [acc][j-half]
    {
      const float* yb = y + ((size_t)(b*L_ + jb + c*64 + quad*8))*H_ + c16;
      #pragma unroll
      for (int jj = 0; jj < 8; ++jj) {
        yb00[jj] = (short)f2bf(yb[(size_t)jj*H_ + w*16]);
        yb10[jj] = (short)f2bf(yb[(size_t)jj*H_ + (w+4)*16]);
      }
      const float* yb2 = yb + (size_t)32*H_;
      #pragma unroll
      for (int jj = 0; jj < 8; ++jj) {
        yb01[jj] = (short)f2bf(yb2[(size_t)jj*H_ + w*16]);
        yb11[jj] = (short)f2bf(yb2[(size_t)jj*H_ + (w+4)*16]);
      }
    }
    if (c < 2) {
      #pragma unroll
      for (int it = 0; it < 8; ++it) {
        int idx = it*256 + tid; int r = idx >> 5; int k4 = (idx & 31) * 4;
        rp[it] = *(const float4v*)(yp + ((size_t)(b*L_ + jb + (c+1)*64 + r))*H_ + k4);
      }
      if (tid < 64) ymb = ymask[b*L_ + jb + (c+1)*64 + tid];
    }

    float sA0 = 0.f, sB0 = 0.f, sA1 = 0.f, sB1 = 0.f;
    {
      const float* yr0 = yp_s[u];
      const float* yr1 = yp_s[u + 32];
      const float* xr  = xp_s[t];
      #pragma unroll 2
      for (int k = 0; k < 128; k += 4) {
        float4v yv0 = *(const float4v*)&yr0[k];
        float4v yv1 = *(const float4v*)&yr1[k];
        float4v xv  = *(const float4v*)&xr[k];
        float4v vv  = *(const float4v*)&v2_s[k];
        sA0 -= vv[0] * __builtin_amdgcn_rcpf(__builtin_fmaf(xv[0], yv0[0], 1.f));
        sB0 -= vv[1] * __builtin_amdgcn_rcpf(__builtin_fmaf(xv[1], yv0[1], 1.f));
        sA0 -= vv[2] * __builtin_amdgcn_rcpf(__builtin_fmaf(xv[2], yv0[2], 1.f));
        sB0 -= vv[3] * __builtin_amdgcn_rcpf(__builtin_fmaf(xv[3], yv0[3], 1.f));
        sA1 -= vv[0] * __builtin_amdgcn_rcpf(__builtin_fmaf(xv[0], yv1[0], 1.f));
        sB1 -= vv[1] * __builtin_amdgcn_rcpf(__builtin_fmaf(xv[1], yv1[1], 1.f));
        sA1 -= vv[2] * __builtin_amdgcn_rcpf(__builtin_fmaf(xv[2], yv1[2], 1.f));
        sB1 -= vv[3] * __builtin_amdgcn_rcpf(__builtin_fmaf(xv[3], yv1[3], 1.f));
      }
    }
    float ym0 = ym_s[u], ym1 = ym_s[u + 32];
    float s0 = (svc + sA0 + sB0) * xmv * ym0;
    float s1 = (svc + sA1 + sB1) * xmv * ym1;
    if (ym0 == 0.f) s0 = -__builtin_inff();
    if (ym1 == 0.f) s1 = -__builtin_inff();
    float mc = fmaxf(s0, s1);
    #pragma unroll
    for (int off = 16; off >= 1; off >>= 1) mc = fmaxf(mc, __shfl_xor(mc, off));
    float mnew = fmaxf(mrun, mc);
    float p0 = __expf(s0 - mnew);
    float p1 = __expf(s1 - mnew);
    float sc = __expf(mrun - mnew);
    float ps = p0 + p1;
    #pragma unroll
    for (int off = 16; off >= 1; off >>= 1) ps += __shfl_xor(ps, off);
    lrun = lrun * sc + ps;
    mrun = mnew;
    p_s0[t][u] = f2bf(p0);
    p_s1[t][u] = f2bf(p1);
    if (u == 0) sc_s[t] = sc;
    __syncthreads();
    short8 pf0 = *(const short8*)&p_s0[c16][quad*8];
    short8 pf1 = *(const short8*)&p_s1[c16][quad*8];
    float4v scv;
    #pragma unroll
    for (int r = 0; r < 4; ++r) scv[r] = sc_s[quad*4 + r];
    acc0 *= scv; acc1 *= scv;
    acc0 = __builtin_amdgcn_mfma_f32_16x16x32_bf16(pf0, yb00, acc0, 0,0,0);
    acc0 = __builtin_amdgcn_mfma_f32_16x16x32_bf16(pf1, yb01, acc0, 0,0,0);
    acc1 = __builtin_amdgcn_mfma_f32_16x16x32_bf16(pf0, yb10, acc1, 0,0,0);
    acc1 = __builtin_amdgcn_mfma_f32_16x16x32_bf16(pf1, yb11, acc1, 0,0,0);
  }
  float* ctp = ctpbase + (size_t)jh*393216;
  if (quad < 2) {
    #pragma unroll
    for (int r = 0; r < 4; ++r) {
      int row = b*L_ + t0 + quad*4 + r;
      ctp[(size_t)row*H_ + w*16 + c16]     = acc0[r];
      ctp[(size_t)row*H_ + (w+4)*16 + c16] = acc1[r];
    }
  }
  if (u == 0) {
    int row = b*L_ + t0 + t;
    ml[(jh*2+0)*3072 + row] = mrun;
    ml[(jh*2+1)*3072 + row] = lrun;
  }
}

// R20 fused gate1 + W_ih GEMM; R22: 2-way softmax merge (j-split halved).
__global__ __launch_bounds__(256) void gatefuse_kernel(
    const float* __restrict__ x,
    const float* __restrict__ ctpbase, const float* __restrict__ ml,
    const float* __restrict__ Wg_w, const float* __restrict__ Wg_b,
    const float* __restrict__ Wih, const float* __restrict__ b_ih,
    const float* __restrict__ b_hh,
    float* __restrict__ gx)
{
  constexpr int K = 256, KP = 258;
  __shared__ __align__(16) unsigned short in_s[16*KP];   // merge bf16
  __shared__ __align__(16) unsigned short gt_s[16*KP];   // lstm_in bf16
  const int tid  = threadIdx.x;
  const int w    = tid >> 6;
  const int l    = tid & 63;
  const int c    = l & 15;
  const int quad = l >> 4;
  const int row0 = blockIdx.x * 16;

  // ---- staging: merge = [x | 2-way softmax-merged ct] (16 rows x 256) ----
  #pragma unroll
  for (int it = 0; it < 4; ++it) {
    int idx = it*256 + tid;
    int r = idx >> 6;          // 0..15
    int k = (idx & 63) * 4;    // 0..252
    int row = row0 + r;
    float4v f;
    if (k < 128) {
      f = *(const float4v*)(x + (size_t)row*128 + k);
    } else {
      float m0 = ml[       row], l0 = ml[  3072 + row];
      float m1 = ml[2*3072+row], l1 = ml[3*3072 + row];
      float mm = fmaxf(m0, m1);
      float e0 = __expf(m0-mm), e1 = __expf(m1-mm);
      float inv = __fdividef(1.f, l0*e0 + l1*e1);
      size_t off = (size_t)row*128 + (k-128);
      float4v v0 = *(const float4v*)(ctpbase           + off);
      float4v v1 = *(const float4v*)(ctpbase + 393216  + off);
      f[0] = (v0[0]*e0 + v1[0]*e1)*inv;
      f[1] = (v0[1]*e0 + v1[1]*e1)*inv;
      f[2] = (v0[2]*e0 + v1[2]*e1)*inv;
      f[3] = (v0[3]*e0 + v1[3]*e1)*inv;
    }
    unsigned int p0 = (unsigned int)f2bf(f[0]) | ((unsigned int)f2bf(f[1]) << 16);
    unsigned int p1 = (unsigned int)f2bf(f[2]) | ((unsigned int)f2bf(f[3]) << 16);
    *(unsigned int*)&in_s[r*KP + k]     = p0;
    *(unsigned int*)&in_s[r*KP + k + 2] = p1;
  }

  const float4v z4 = {0.f,0.f,0.f,0.f};
  short8 bfr[2][8];

  // preload Wg pass 0
  {
    const int n0 = w*16 + c;
    #pragma unroll
    for (int kt = 0; kt < 8; ++kt) {
      const float* src = Wg_w + (size_t)n0*K + kt*32 + quad*8;
      float4v f0 = *(const float4v*)(src);
      float4v f1 = *(const float4v*)(src + 4);
      short8 v;
      v[0]=(short)f2bf(f0[0]); v[1]=(short)f2bf(f0[1]); v[2]=(short)f2bf(f0[2]); v[3]=(short)f2bf(f0[3]);
      v[4]=(short)f2bf(f1[0]); v[5]=(short)f2bf(f1[1]); v[6]=(short)f2bf(f1[2]); v[7]=(short)f2bf(f1[3]);
      bfr[0][kt] = v;
    }
  }
  __syncthreads();

  // ---- Phase A: Wg GEMM, 4 column passes, write lstm_in bf16 to gt_s ----
  #pragma unroll
  for (int obi = 0; obi < 4; ++obi) {
    const int cur = obi & 1;
    const int n = obi*64 + w*16 + c;
    if (obi < 3) {
      const int nn = (obi+1)*64 + w*16 + c;
      #pragma unroll
      for (int kt = 0; kt < 8; ++kt) {
        const float* src = Wg_w + (size_t)nn*K + kt*32 + quad*8;
        float4v f0 = *(const float4v*)(src);
        float4v f1 = *(const float4v*)(src + 4);
        short8 v;
        v[0]=(short)f2bf(f0[0]); v[1]=(short)f2bf(f0[1]); v[2]=(short)f2bf(f0[2]); v[3]=(short)f2bf(f0[3]);
        v[4]=(short)f2bf(f1[0]); v[5]=(short)f2bf(f1[1]); v[6]=(short)f2bf(f1[2]); v[7]=(short)f2bf(f1[3]);
        bfr[cur^1][kt] = v;
      }
    }
    float4v acc0 = z4;
    #pragma unroll
    for (int kt = 0; kt < 8; ++kt) {
      short8 a0 = *(const short8*)&in_s[c*KP + kt*32 + quad*8];
      acc0 = __builtin_amdgcn_mfma_f32_16x16x32_bf16(a0, bfr[cur][kt], acc0, 0,0,0);
    }
    float bv = Wg_b[n];
    #pragma unroll
    for (int r = 0; r < 4; ++r) {
      int m = quad*4 + r;
      float val = acc0[r] + bv;
      float mg = bflo((unsigned int)in_s[m*KP + n]);
      gt_s[m*KP + n] = f2bf(fsig(val) * mg);
    }
  }

  // preload Wih pass 0
  {
    const int n0 = w*16 + c;
    #pragma unroll
    for (int kt = 0; kt < 8; ++kt) {
      const float* src = Wih + (size_t)n0*K + kt*32 + quad*8;
      float4v f0 = *(const float4v*)(src);
      float4v f1 = *(const float4v*)(src + 4);
      short8 v;
      v[0]=(short)f2bf(f0[0]); v[1]=(short)f2bf(f0[1]); v[2]=(short)f2bf(f0[2]); v[3]=(short)f2bf(f0[3]);
      v[4]=(short)f2bf(f1[0]); v[5]=(short)f2bf(f1[1]); v[6]=(short)f2bf(f1[2]); v[7]=(short)f2bf(f1[3]);
      bfr[0][kt] = v;
    }
  }
  __syncthreads();

  // ---- Phase B: W_ih GEMM from gt_s, 8 column passes, act==3 scatter ----
  #pragma unroll
  for (int oby = 0; oby < 8; ++oby) {
    const int cur = oby & 1;
    const int n = oby*64 + w*16 + c;
    if (oby < 7) {
      const int nn = (oby+1)*64 + w*16 + c;
      #pragma unroll
      for (int kt = 0; kt < 8; ++kt) {
        const float* src = Wih + (size_t)nn*K + kt*32 + quad*8;
        float4v f0 = *(const float4v*)(src);
        float4v f1 = *(const float4v*)(src + 4);
        short8 v;
        v[0]=(short)f2bf(f0[0]); v[1]=(short)f2bf(f0[1]); v[2]=(short)f2bf(f0[2]); v[3]=(short)f2bf(f0[3]);
        v[4]=(short)f2bf(f1[0]); v[5]=(short)f2bf(f1[1]); v[6]=(short)f2bf(f1[2]); v[7]=(short)f2bf(f1[3]);
        bfr[cur^1][kt] = v;
      }
    }
    float4v acc0 = z4;
    #pragma unroll
    for (int kt = 0; kt < 8; ++kt) {
      short8 a0 = *(const short8*)&gt_s[c*KP + kt*32 + quad*8];
      acc0 = __builtin_amdgcn_mfma_f32_16x16x32_bf16(a0, bfr[cur][kt], acc0, 0,0,0);
    }
    float bv = b_ih[n] + b_hh[n];
    #pragma unroll
    for (int r = 0; r < 4; ++r) {
      int m = quad*4 + r;
      float val = acc0[r] + bv;
      gx[(size_t)(row0+m)*512 + (n & 127)*4 + (n >> 7)] = val;
    }
  }
}

// LSTM scan, R20 (measured 148.6us): i8 MFMA matvec with C-in chained
// K-half MFMAs; i,g issued first so their gate math overlaps f,o issue.
__global__ __launch_bounds__(512) void lstm_kernel(
    const float* __restrict__ gx, const float* __restrict__ Whh,
    float* __restrict__ out)
{
  __shared__ __align__(16) unsigned char h8_s[2][128];   // i8 h, double buffer
  const int tid  = threadIdx.x;
  const int b    = blockIdx.x;
  const int w    = tid >> 6;
  const int l    = tid & 63;
  const int col  = l & 15;
  const int quad = l >> 4;

  int4v bq[4][2];
  float dq[4];
  #pragma unroll
  for (int nt = 0; nt < 4; ++nt) {
    const int n = nt*128 + w*16 + col;
    const float* src = Whh + (size_t)n*H_;
    float4v f[8];
    #pragma unroll
    for (int t8 = 0; t8 < 2; ++t8)
      #pragma unroll
      for (int i = 0; i < 4; ++i)
        f[t8*4+i] = *(const float4v*)(src + t8*64 + quad*16 + i*4);
    float mx = 0.f;
    #pragma unroll
    for (int i = 0; i < 8; ++i)
      mx = fmaxf(mx, fmaxf(fmaxf(fabsf(f[i][0]), fabsf(f[i][1])),
                           fmaxf(fabsf(f[i][2]), fabsf(f[i][3]))));
    mx = fmaxf(mx, __shfl_xor(mx, 16));
    mx = fmaxf(mx, __shfl_xor(mx, 32));
    const float qs = 127.f / mx;
    dq[nt] = mx * (1.f/16129.f);     // rowmax/(127*127)
    #pragma unroll
    for (int t8 = 0; t8 < 2; ++t8) {
      int4v bb;
      #pragma unroll
      for (int d = 0; d < 4; ++d) {
        float4v ff = f[t8*4+d];
        int q0 = (int)rintf(ff[0]*qs), q1 = (int)rintf(ff[1]*qs);
        int q2 = (int)rintf(ff[2]*qs), q3 = (int)rintf(ff[3]*qs);
        bb[d] = (q0 & 255) | ((q1 & 255) << 8) | ((q2 & 255) << 16) | ((q3 & 255) << 24);
      }
      bq[nt][t8] = bb;
    }
  }

  if (tid < 256) ((unsigned char*)h8_s)[tid] = 0;
  float cst = 0.f;
  const int goff = w*16 + col;
  const float* gbase = gx + (size_t)b*L_*512 + goff*4;
  float* outp = out + (size_t)b*L_*H_ + goff;
  float4v gbuf[4];
  #pragma unroll
  for (int s = 0; s < 4; ++s)
    gbuf[s] = *(const float4v*)(gbase + (size_t)s*512);
  const int4v zi = {0,0,0,0};
  const float NL2E  = -1.4426950408889634f;   // -log2(e)
  const float P2L2E =  2.8853900817779268f;   //  2*log2(e)
  __syncthreads();

  for (int t4 = 0; t4 < L_; t4 += 4) {
    #pragma unroll
    for (int s = 0; s < 4; ++s) {
      const int tstep = t4 + s;
      const unsigned char* hb = h8_s[s & 1];
      int4v a0 = *(const int4v*)&hb[     quad*16];
      int4v a1 = *(const int4v*)&hb[64 + quad*16];
      float4v gcur = gbuf[s];
      if (tstep + 4 < L_)
        gbuf[s] = *(const float4v*)(gbase + (size_t)(tstep+4)*512);
      // i,g first so their gate math overlaps f,o issue
      int4v c0 = __builtin_amdgcn_mfma_i32_16x16x64_i8(a0, bq[0][0], zi, 0,0,0);
      int4v c2 = __builtin_amdgcn_mfma_i32_16x16x64_i8(a0, bq[2][0], zi, 0,0,0);
      c0 = __builtin_amdgcn_mfma_i32_16x16x64_i8(a1, bq[0][1], c0, 0,0,0);
      c2 = __builtin_amdgcn_mfma_i32_16x16x64_i8(a1, bq[2][1], c2, 0,0,0);
      int4v c1 = __builtin_amdgcn_mfma_i32_16x16x64_i8(a0, bq[1][0], zi, 0,0,0);
      int4v c3 = __builtin_amdgcn_mfma_i32_16x16x64_i8(a0, bq[3][0], zi, 0,0,0);
      c1 = __builtin_amdgcn_mfma_i32_16x16x64_i8(a1, bq[1][1], c1, 0,0,0);
      c3 = __builtin_amdgcn_mfma_i32_16x16x64_i8(a1, bq[3][1], c3, 0,0,0);
      float ig = __builtin_amdgcn_rcpf(1.f + __builtin_amdgcn_exp2f(
                   NL2E*__builtin_fmaf((float)c0[0], dq[0], gcur[0])));
      float gg = 1.f - 2.f*__builtin_amdgcn_rcpf(__builtin_amdgcn_exp2f(
                   P2L2E*__builtin_fmaf((float)c2[0], dq[2], gcur[2])) + 1.f);
      float igg = ig * gg;
      float fg = __builtin_amdgcn_rcpf(1.f + __builtin_amdgcn_exp2f(
                   NL2E*__builtin_fmaf((float)c1[0], dq[1], gcur[1])));
      float og = __builtin_amdgcn_rcpf(1.f + __builtin_amdgcn_exp2f(
                   NL2E*__builtin_fmaf((float)c3[0], dq[3], gcur[3])));
      cst = fg*cst + igg;
      float hn = og * (1.f - 2.f*__builtin_amdgcn_rcpf(
                   __builtin_amdgcn_exp2f(P2L2E*cst) + 1.f));
      if (quad == 0) {
        outp[(size_t)tstep*H_] = hn;
        int q = (int)rintf(hn * 127.f);
        h8_s[(s+1)&1][goff] = (unsigned char)q;
      }
      barrier_lds();
    }
  }
}

extern "C" void kernel_launch(void* const* d_in, const int* in_sizes, int n_in,
                              void* d_out, int out_size, void* d_ws, size_t ws_size,
                              hipStream_t stream)
{
  (void)in_sizes; (void)n_in; (void)out_size; (void)ws_size;
  const float* x     = (const float*)d_in[0];
  const unsigned char* xm = (const unsigned char*)d_in[1];
  const float* y     = (const float*)d_in[2];
  const unsigned char* ym = (const unsigned char*)d_in[3];
  const float* Wq_w  = (const float*)d_in[4];
  const float* Wq_b  = (const float*)d_in[5];
  const float* Wup_w = (const float*)d_in[6];
  const float* Wup_b = (const float*)d_in[7];
  const float* Wvp_b = (const float*)d_in[9];
  const float* V_w   = (const float*)d_in[10];
  const float* V_b   = (const float*)d_in[11];
  const float* Wg_w  = (const float*)d_in[12];
  const float* Wg_b  = (const float*)d_in[13];
  const float* W_ih  = (const float*)d_in[14];
  const float* W_hh  = (const float*)d_in[15];
  const float* b_ih  = (const float*)d_in[16];
  const float* b_hh  = (const float*)d_in[17];
  float* out = (float*)d_out;

  float* wsf    = (float*)d_ws;
  float* xp_ws  = wsf;                   // [3072][128]  Ex
  float* yp_ws  = xp_ws + 393216;        // [3072][128]  Ey
  float* ctp_ws = yp_ws + 393216;        // [2][3072][128] partials
  float* gx_ws  = ctp_ws + 2*393216;     // [3072][512] gate-interleaved
  float* ml_ws  = gx_ws + 1572864;       // [4][3072]   (m_i, l_i)

  proj_mfma_kernel<<<dim3(384),256,0,stream>>>(x, y, Wup_w, Wup_b, Wq_w, Wq_b, Wvp_b, xp_ws, yp_ws);
  attn_kernel<<<dim3(48,8,2),256,0,stream>>>(xp_ws, yp_ws, y, xm, ym, V_w, V_b, ctp_ws, ml_ws);
  gatefuse_kernel<<<dim3(192),256,0,stream>>>(x, ctp_ws, ml_ws, Wg_w, Wg_b, W_ih, b_ih, b_hh, gx_ws);
  lstm_kernel<<<dim3(8),512,0,stream>>>(gx_ws, W_hh, out);
}

// Round 12
// 299.579 us; speedup vs baseline: 1.0104x; 1.0104x over previous
//
#include <hip/hip_runtime.h>
#include <hip/hip_bf16.h>
#include <math.h>

typedef __attribute__((ext_vector_type(4))) float  float4v;
typedef __attribute__((ext_vector_type(2))) float  float2v;
typedef __attribute__((ext_vector_type(8))) short  short8;
typedef __attribute__((ext_vector_type(4))) int    int4v;

#define B_ 8
#define L_ 384
#define H_ 128

__device__ __forceinline__ float bflo(unsigned int u){ unsigned int t = u << 16; float f; __builtin_memcpy(&f,&t,4); return f; }
__device__ __forceinline__ unsigned short f2bf(float f){
  unsigned int t; __builtin_memcpy(&t,&f,4);
  return (unsigned short)((t + 0x7fffu + ((t>>16)&1u)) >> 16);
}
__device__ __forceinline__ float fsig(float x){ return __fdividef(1.f, 1.f + __expf(-x)); }

// lgkm-only barrier: LDS ordering without draining in-flight global loads/stores
__device__ __forceinline__ void barrier_lds(){
  asm volatile("s_waitcnt lgkmcnt(0)\n\ts_barrier" ::: "memory");
}

// ---------------- MFMA row-GEMM ----------------
// act==0: linear. act==3: gate-interleaved scatter. act==4: exp2(C2*val).
template<int K>
__device__ __forceinline__ void mfma_rowgemm_body(
    unsigned short* in_s,
    const float* __restrict__ inA,
    const float* __restrict__ W, const float* __restrict__ bias,
    const float* __restrict__ bias2, float* __restrict__ out,
    int Ntotal, int act, int row0, int ob)
{
  constexpr int KP = K + 2;
  const int tid  = threadIdx.x;
  const int w    = tid >> 6;
  const int l    = tid & 63;
  const int c    = l & 15;
  const int quad = l >> 4;

  #pragma unroll
  for (int it = 0; it < K/32; ++it) {
    int idx = it*256 + tid;
    int r = idx / (K/4);
    int k = (idx % (K/4)) * 4;
    float4v f = *(const float4v*)(inA + (size_t)(row0+r)*K + k);
    unsigned int p0 = (unsigned int)f2bf(f.x) | ((unsigned int)f2bf(f.y) << 16);
    unsigned int p1 = (unsigned int)f2bf(f.z) | ((unsigned int)f2bf(f.w) << 16);
    *(unsigned int*)&in_s[r*KP + k]     = p0;
    *(unsigned int*)&in_s[r*KP + k + 2] = p1;
  }

  const int n = ob + w*16 + c;
  short8 bfr[K/32];
  #pragma unroll
  for (int kt = 0; kt < K/32; ++kt) {
    const float* src = W + (size_t)n*K + kt*32 + quad*8;
    float4v f0 = *(const float4v*)(src);
    float4v f1 = *(const float4v*)(src + 4);
    short8 v;
    v[0]=(short)f2bf(f0[0]); v[1]=(short)f2bf(f0[1]); v[2]=(short)f2bf(f0[2]); v[3]=(short)f2bf(f0[3]);
    v[4]=(short)f2bf(f1[0]); v[5]=(short)f2bf(f1[1]); v[6]=(short)f2bf(f1[2]); v[7]=(short)f2bf(f1[3]);
    bfr[kt] = v;
  }
  __syncthreads();

  const float4v z4 = {0.f,0.f,0.f,0.f};
  float4v acc0 = z4, acc1 = z4;
  #pragma unroll
  for (int kt = 0; kt < K/32; ++kt) {
    short8 a0 = *(const short8*)&in_s[(c     )*KP + kt*32 + quad*8];
    short8 a1 = *(const short8*)&in_s[(16 + c)*KP + kt*32 + quad*8];
    acc0 = __builtin_amdgcn_mfma_f32_16x16x32_bf16(a0, bfr[kt], acc0, 0,0,0);
    acc1 = __builtin_amdgcn_mfma_f32_16x16x32_bf16(a1, bfr[kt], acc1, 0,0,0);
  }

  const float C2 = 2.8853900817779268f;   // 2*log2(e)
  float bv = bias[n] + (bias2 ? bias2[n] : 0.f);
  #pragma unroll
  for (int mt = 0; mt < 2; ++mt) {
    float4v A = mt ? acc1 : acc0;
    #pragma unroll
    for (int r = 0; r < 4; ++r) {
      int m = mt*16 + quad*4 + r;
      float val = A[r] + bv;
      if (act == 4)
        val = __builtin_amdgcn_exp2f(C2 * val);
      if (act == 3)
        out[(size_t)(row0+m)*Ntotal + (n & 127)*4 + (n >> 7)] = val;
      else
        out[(size_t)(row0+m)*Ntotal + n] = val;
    }
  }
}

// Projections emit Ex = exp2(C2*x_proj), Ey = exp2(C2*y_proj2)
__global__ __launch_bounds__(256) void proj_mfma_kernel(
    const float* __restrict__ x, const float* __restrict__ y,
    const float* __restrict__ Wup_w, const float* __restrict__ Wup_b,
    const float* __restrict__ Wq_w, const float* __restrict__ Wq_b,
    const float* __restrict__ Wvp_b,
    float* __restrict__ xp, float* __restrict__ yp)
{
  __shared__ __align__(16) unsigned short in_s[32*130];
  int bx = blockIdx.x;
  if (bx < 192)
    mfma_rowgemm_body<128>(in_s, x, Wup_w, Wup_b, nullptr,
                           xp, 128, 4, (bx>>1)*32, (bx&1)*64);
  else {
    bx -= 192;
    mfma_rowgemm_body<128>(in_s, y, Wq_w, Wq_b, Wvp_b,
                           yp, 128, 4, (bx>>1)*32, (bx&1)*64);
  }
}

// Fused additive attention — R22 form (best measured, 301.0 us total).
// Stage-then-LDS read structure (R21 proved direct gather is -54us worse);
// j-split 2 (R22 proved 4->2 neutral, kept for lower ctp traffic).
__global__ __launch_bounds__(256) void attn_kernel(
    const float* __restrict__ xp, const float* __restrict__ yp,
    const float* __restrict__ y, const unsigned char* __restrict__ xmask,
    const unsigned char* __restrict__ ymask, const float* __restrict__ Vw,
    const float* __restrict__ Vb,
    float* __restrict__ ctpbase, float* __restrict__ ml)
{
  __shared__ __align__(16) float xp_s[8][128];
  __shared__ __align__(16) float v2_s[128];
  __shared__ __align__(16) float yp_s[32][132];
  __shared__ __align__(16) unsigned short p_s[16][40];   // bf16 A-frag: rows 8-15 unused
  __shared__ float sc_s[16];
  __shared__ float xm_s[8];
  __shared__ float ym_s[32];
  __shared__ float sv_s;
  const int tid = threadIdx.x;
  const int b   = blockIdx.y;
  const int t0  = blockIdx.x * 8;
  const int jh  = blockIdx.z;      // 2 splits x 192 j
  const int jb  = jh * 192;
  const int w    = tid >> 6;       // wave
  const int l    = tid & 63;
  const int c16  = l & 15;
  const int quad = l >> 4;
  {
    int r = tid >> 5, k4 = (tid & 31) * 4;
    float4v f = *(const float4v*)(xp + ((size_t)(b*L_ + t0 + r))*H_ + k4);
    *(float4v*)&xp_s[r][k4] = f;
    if (tid < 32) {
      float4v v = *(const float4v*)(Vw + tid*4);
      float4v v2; v2[0]=2.f*v[0]; v2[1]=2.f*v[1]; v2[2]=2.f*v[2]; v2[3]=2.f*v[3];
      *(float4v*)&v2_s[tid*4] = v2;
    }
    if (tid < 8) xm_s[tid] = xmask[b*L_ + t0 + tid] ? 0.f : 1.f;
    if (tid < 16) sc_s[tid] = 0.f;
    for (int i = 320 + tid; i < 640; i += 256) ((unsigned short*)p_s)[i] = 0;
  }
  __syncthreads();
  if (tid < 32) {
    float4v v = *(const float4v*)&v2_s[tid*4];
    float sm = (v[0]+v[1]) + (v[2]+v[3]);
    #pragma unroll
    for (int off = 16; off >= 1; off >>= 1) sm += __shfl_xor(sm, off);
    if (tid == 0) sv_s = 0.5f*sm + Vb[0];
  }

  float4v rp[4];
  unsigned char ymb = 0;
  {
    #pragma unroll
    for (int it = 0; it < 4; ++it) {
      int idx = it*256 + tid; int r = idx >> 5; int k4 = (idx & 31) * 4;
      rp[it] = *(const float4v*)(yp + ((size_t)(b*L_ + jb + r))*H_ + k4);
    }
    if (tid < 32) ymb = ymask[b*L_ + jb + tid];
  }

  const int t = tid >> 5, u = tid & 31;
  float mrun = -__builtin_inff(), lrun = 0.f;
  const float4v z4 = {0.f,0.f,0.f,0.f};
  float4v acc0 = z4, acc1 = z4;    // ct C-regs: ntiles w and w+4
  float svc = 0.f, xmv = 0.f;

  for (int c = 0; c < 6; ++c) {
    __syncthreads();
    #pragma unroll
    for (int it = 0; it < 4; ++it) {
      int idx = it*256 + tid; int r = idx >> 5; int k4 = (idx & 31) * 4;
      *(float4v*)&yp_s[r][k4] = rp[it];
    }
    if (tid < 32) ym_s[tid] = ymb ? 0.f : 1.f;
    __syncthreads();
    if (c == 0) { svc = sv_s; xmv = xm_s[t]; }
    short8 yb0, yb1;
    {
      const float* ybase = y + ((size_t)(b*L_ + jb + c*32 + quad*8))*H_ + c16;
      #pragma unroll
      for (int jj = 0; jj < 8; ++jj) {
        yb0[jj] = (short)f2bf(ybase[(size_t)jj*H_ + w*16]);
        yb1[jj] = (short)f2bf(ybase[(size_t)jj*H_ + (w+4)*16]);
      }
    }
    if (c < 5) {
      #pragma unroll
      for (int it = 0; it < 4; ++it) {
        int idx = it*256 + tid; int r = idx >> 5; int k4 = (idx & 31) * 4;
        rp[it] = *(const float4v*)(yp + ((size_t)(b*L_ + jb + (c+1)*32 + r))*H_ + k4);
      }
      if (tid < 32) ymb = ymask[b*L_ + jb + (c+1)*32 + tid];
    }

    float sA = 0.f, sB = 0.f;
    {
      const float* yr = yp_s[u];
      const float* xr = xp_s[t];
      #pragma unroll 4
      for (int k = 0; k < 128; k += 4) {
        float4v yv = *(const float4v*)&yr[k];
        float4v xv = *(const float4v*)&xr[k];
        float4v vv = *(const float4v*)&v2_s[k];
        sA -= vv[0] * __builtin_amdgcn_rcpf(__builtin_fmaf(xv[0], yv[0], 1.f));
        sB -= vv[1] * __builtin_amdgcn_rcpf(__builtin_fmaf(xv[1], yv[1], 1.f));
        sA -= vv[2] * __builtin_amdgcn_rcpf(__builtin_fmaf(xv[2], yv[2], 1.f));
        sB -= vv[3] * __builtin_amdgcn_rcpf(__builtin_fmaf(xv[3], yv[3], 1.f));
      }
    }
    float ymv = ym_s[u];
    float s = (svc + sA + sB) * xmv * ymv;
    if (ymv == 0.f) s = -__builtin_inff();
    float mc = s;
    #pragma unroll
    for (int off = 16; off >= 1; off >>= 1) mc = fmaxf(mc, __shfl_xor(mc, off));
    float mnew = fmaxf(mrun, mc);
    float p  = __expf(s - mnew);
    float sc = __expf(mrun - mnew);
    float ps = p;
    #pragma unroll
    for (int off = 16; off >= 1; off >>= 1) ps += __shfl_xor(ps, off);
    lrun = lrun * sc + ps;
    mrun = mnew;
    p_s[t][u] = f2bf(p);
    if (u == 0) sc_s[t] = sc;
    __syncthreads();
    short8 pf = *(const short8*)&p_s[c16][quad*8];
    float4v scv;
    #pragma unroll
    for (int r = 0; r < 4; ++r) scv[r] = sc_s[quad*4 + r];
    acc0 *= scv; acc1 *= scv;
    acc0 = __builtin_amdgcn_mfma_f32_16x16x32_bf16(pf, yb0, acc0, 0,0,0);
    acc1 = __builtin_amdgcn_mfma_f32_16x16x32_bf16(pf, yb1, acc1, 0,0,0);
  }
  float* ctp = ctpbase + (size_t)jh*393216;
  if (quad < 2) {
    #pragma unroll
    for (int r = 0; r < 4; ++r) {
      int row = b*L_ + t0 + quad*4 + r;
      ctp[(size_t)row*H_ + w*16 + c16]     = acc0[r];
      ctp[(size_t)row*H_ + (w+4)*16 + c16] = acc1[r];
    }
  }
  if (u == 0) {
    int row = b*L_ + t0 + t;
    ml[(jh*2+0)*3072 + row] = mrun;
    ml[(jh*2+1)*3072 + row] = lrun;
  }
}

// R20 fused gate1 + W_ih GEMM; R22: 2-way softmax merge (j-split halved).
__global__ __launch_bounds__(256) void gatefuse_kernel(
    const float* __restrict__ x,
    const float* __restrict__ ctpbase, const float* __restrict__ ml,
    const float* __restrict__ Wg_w, const float* __restrict__ Wg_b,
    const float* __restrict__ Wih, const float* __restrict__ b_ih,
    const float* __restrict__ b_hh,
    float* __restrict__ gx)
{
  constexpr int K = 256, KP = 258;
  __shared__ __align__(16) unsigned short in_s[16*KP];   // merge bf16
  __shared__ __align__(16) unsigned short gt_s[16*KP];   // lstm_in bf16
  const int tid  = threadIdx.x;
  const int w    = tid >> 6;
  const int l    = tid & 63;
  const int c    = l & 15;
  const int quad = l >> 4;
  const int row0 = blockIdx.x * 16;

  // ---- staging: merge = [x | 2-way softmax-merged ct] (16 rows x 256) ----
  #pragma unroll
  for (int it = 0; it < 4; ++it) {
    int idx = it*256 + tid;
    int r = idx >> 6;          // 0..15
    int k = (idx & 63) * 4;    // 0..252
    int row = row0 + r;
    float4v f;
    if (k < 128) {
      f = *(const float4v*)(x + (size_t)row*128 + k);
    } else {
      float m0 = ml[       row], l0 = ml[  3072 + row];
      float m1 = ml[2*3072+row], l1 = ml[3*3072 + row];
      float mm = fmaxf(m0, m1);
      float e0 = __expf(m0-mm), e1 = __expf(m1-mm);
      float inv = __fdividef(1.f, l0*e0 + l1*e1);
      size_t off = (size_t)row*128 + (k-128);
      float4v v0 = *(const float4v*)(ctpbase           + off);
      float4v v1 = *(const float4v*)(ctpbase + 393216  + off);
      f[0] = (v0[0]*e0 + v1[0]*e1)*inv;
      f[1] = (v0[1]*e0 + v1[1]*e1)*inv;
      f[2] = (v0[2]*e0 + v1[2]*e1)*inv;
      f[3] = (v0[3]*e0 + v1[3]*e1)*inv;
    }
    unsigned int p0 = (unsigned int)f2bf(f[0]) | ((unsigned int)f2bf(f[1]) << 16);
    unsigned int p1 = (unsigned int)f2bf(f[2]) | ((unsigned int)f2bf(f[3]) << 16);
    *(unsigned int*)&in_s[r*KP + k]     = p0;
    *(unsigned int*)&in_s[r*KP + k + 2] = p1;
  }

  const float4v z4 = {0.f,0.f,0.f,0.f};
  short8 bfr[2][8];

  // preload Wg pass 0
  {
    const int n0 = w*16 + c;
    #pragma unroll
    for (int kt = 0; kt < 8; ++kt) {
      const float* src = Wg_w + (size_t)n0*K + kt*32 + quad*8;
      float4v f0 = *(const float4v*)(src);
      float4v f1 = *(const float4v*)(src + 4);
      short8 v;
      v[0]=(short)f2bf(f0[0]); v[1]=(short)f2bf(f0[1]); v[2]=(short)f2bf(f0[2]); v[3]=(short)f2bf(f0[3]);
      v[4]=(short)f2bf(f1[0]); v[5]=(short)f2bf(f1[1]); v[6]=(short)f2bf(f1[2]); v[7]=(short)f2bf(f1[3]);
      bfr[0][kt] = v;
    }
  }
  __syncthreads();

  // ---- Phase A: Wg GEMM, 4 column passes, write lstm_in bf16 to gt_s ----
  #pragma unroll
  for (int obi = 0; obi < 4; ++obi) {
    const int cur = obi & 1;
    const int n = obi*64 + w*16 + c;
    if (obi < 3) {
      const int nn = (obi+1)*64 + w*16 + c;
      #pragma unroll
      for (int kt = 0; kt < 8; ++kt) {
        const float* src = Wg_w + (size_t)nn*K + kt*32 + quad*8;
        float4v f0 = *(const float4v*)(src);
        float4v f1 = *(const float4v*)(src + 4);
        short8 v;
        v[0]=(short)f2bf(f0[0]); v[1]=(short)f2bf(f0[1]); v[2]=(short)f2bf(f0[2]); v[3]=(short)f2bf(f0[3]);
        v[4]=(short)f2bf(f1[0]); v[5]=(short)f2bf(f1[1]); v[6]=(short)f2bf(f1[2]); v[7]=(short)f2bf(f1[3]);
        bfr[cur^1][kt] = v;
      }
    }
    float4v acc0 = z4;
    #pragma unroll
    for (int kt = 0; kt < 8; ++kt) {
      short8 a0 = *(const short8*)&in_s[c*KP + kt*32 + quad*8];
      acc0 = __builtin_amdgcn_mfma_f32_16x16x32_bf16(a0, bfr[cur][kt], acc0, 0,0,0);
    }
    float bv = Wg_b[n];
    #pragma unroll
    for (int r = 0; r < 4; ++r) {
      int m = quad*4 + r;
      float val = acc0[r] + bv;
      float mg = bflo((unsigned int)in_s[m*KP + n]);
      gt_s[m*KP + n] = f2bf(fsig(val) * mg);
    }
  }

  // preload Wih pass 0
  {
    const int n0 = w*16 + c;
    #pragma unroll
    for (int kt = 0; kt < 8; ++kt) {
      const float* src = Wih + (size_t)n0*K + kt*32 + quad*8;
      float4v f0 = *(const float4v*)(src);
      float4v f1 = *(const float4v*)(src + 4);
      short8 v;
      v[0]=(short)f2bf(f0[0]); v[1]=(short)f2bf(f0[1]); v[2]=(short)f2bf(f0[2]); v[3]=(short)f2bf(f0[3]);
      v[4]=(short)f2bf(f1[0]); v[5]=(short)f2bf(f1[1]); v[6]=(short)f2bf(f1[2]); v[7]=(short)f2bf(f1[3]);
      bfr[0][kt] = v;
    }
  }
  __syncthreads();

  // ---- Phase B: W_ih GEMM from gt_s, 8 column passes, act==3 scatter ----
  #pragma unroll
  for (int oby = 0; oby < 8; ++oby) {
    const int cur = oby & 1;
    const int n = oby*64 + w*16 + c;
    if (oby < 7) {
      const int nn = (oby+1)*64 + w*16 + c;
      #pragma unroll
      for (int kt = 0; kt < 8; ++kt) {
        const float* src = Wih + (size_t)nn*K + kt*32 + quad*8;
        float4v f0 = *(const float4v*)(src);
        float4v f1 = *(const float4v*)(src + 4);
        short8 v;
        v[0]=(short)f2bf(f0[0]); v[1]=(short)f2bf(f0[1]); v[2]=(short)f2bf(f0[2]); v[3]=(short)f2bf(f0[3]);
        v[4]=(short)f2bf(f1[0]); v[5]=(short)f2bf(f1[1]); v[6]=(short)f2bf(f1[2]); v[7]=(short)f2bf(f1[3]);
        bfr[cur^1][kt] = v;
      }
    }
    float4v acc0 = z4;
    #pragma unroll
    for (int kt = 0; kt < 8; ++kt) {
      short8 a0 = *(const short8*)&gt_s[c*KP + kt*32 + quad*8];
      acc0 = __builtin_amdgcn_mfma_f32_16x16x32_bf16(a0, bfr[cur][kt], acc0, 0,0,0);
    }
    float bv = b_ih[n] + b_hh[n];
    #pragma unroll
    for (int r = 0; r < 4; ++r) {
      int m = quad*4 + r;
      float val = acc0[r] + bv;
      gx[(size_t)(row0+m)*512 + (n & 127)*4 + (n >> 7)] = val;
    }
  }
}

// LSTM scan, R20 (measured 148.5us): i8 MFMA matvec with C-in chained
// K-half MFMAs; i,g issued first so their gate math overlaps f,o issue.
__global__ __launch_bounds__(512) void lstm_kernel(
    const float* __restrict__ gx, const float* __restrict__ Whh,
    float* __restrict__ out)
{
  __shared__ __align__(16) unsigned char h8_s[2][128];   // i8 h, double buffer
  const int tid  = threadIdx.x;
  const int b    = blockIdx.x;
  const int w    = tid >> 6;
  const int l    = tid & 63;
  const int col  = l & 15;
  const int quad = l >> 4;

  int4v bq[4][2];
  float dq[4];
  #pragma unroll
  for (int nt = 0; nt < 4; ++nt) {
    const int n = nt*128 + w*16 + col;
    const float* src = Whh + (size_t)n*H_;
    float4v f[8];
    #pragma unroll
    for (int t8 = 0; t8 < 2; ++t8)
      #pragma unroll
      for (int i = 0; i < 4; ++i)
        f[t8*4+i] = *(const float4v*)(src + t8*64 + quad*16 + i*4);
    float mx = 0.f;
    #pragma unroll
    for (int i = 0; i < 8; ++i)
      mx = fmaxf(mx, fmaxf(fmaxf(fabsf(f[i][0]), fabsf(f[i][1])),
                           fmaxf(fabsf(f[i][2]), fabsf(f[i][3]))));
    mx = fmaxf(mx, __shfl_xor(mx, 16));
    mx = fmaxf(mx, __shfl_xor(mx, 32));
    const float qs = 127.f / mx;
    dq[nt] = mx * (1.f/16129.f);     // rowmax/(127*127)
    #pragma unroll
    for (int t8 = 0; t8 < 2; ++t8) {
      int4v bb;
      #pragma unroll
      for (int d = 0; d < 4; ++d) {
        float4v ff = f[t8*4+d];
        int q0 = (int)rintf(ff[0]*qs), q1 = (int)rintf(ff[1]*qs);
        int q2 = (int)rintf(ff[2]*qs), q3 = (int)rintf(ff[3]*qs);
        bb[d] = (q0 & 255) | ((q1 & 255) << 8) | ((q2 & 255) << 16) | ((q3 & 255) << 24);
      }
      bq[nt][t8] = bb;
    }
  }

  if (tid < 256) ((unsigned char*)h8_s)[tid] = 0;
  float cst = 0.f;
  const int goff = w*16 + col;
  const float* gbase = gx + (size_t)b*L_*512 + goff*4;
  float* outp = out + (size_t)b*L_*H_ + goff;
  float4v gbuf[4];
  #pragma unroll
  for (int s = 0; s < 4; ++s)
    gbuf[s] = *(const float4v*)(gbase + (size_t)s*512);
  const int4v zi = {0,0,0,0};
  const float NL2E  = -1.4426950408889634f;   // -log2(e)
  const float P2L2E =  2.8853900817779268f;   //  2*log2(e)
  __syncthreads();

  for (int t4 = 0; t4 < L_; t4 += 4) {
    #pragma unroll
    for (int s = 0; s < 4; ++s) {
      const int tstep = t4 + s;
      const unsigned char* hb = h8_s[s & 1];
      int4v a0 = *(const int4v*)&hb[     quad*16];
      int4v a1 = *(const int4v*)&hb[64 + quad*16];
      float4v gcur = gbuf[s];
      if (tstep + 4 < L_)
        gbuf[s] = *(const float4v*)(gbase + (size_t)(tstep+4)*512);
      // i,g first so their gate math overlaps f,o issue
      int4v c0 = __builtin_amdgcn_mfma_i32_16x16x64_i8(a0, bq[0][0], zi, 0,0,0);
      int4v c2 = __builtin_amdgcn_mfma_i32_16x16x64_i8(a0, bq[2][0], zi, 0,0,0);
      c0 = __builtin_amdgcn_mfma_i32_16x16x64_i8(a1, bq[0][1], c0, 0,0,0);
      c2 = __builtin_amdgcn_mfma_i32_16x16x64_i8(a1, bq[2][1], c2, 0,0,0);
      int4v c1 = __builtin_amdgcn_mfma_i32_16x16x64_i8(a0, bq[1][0], zi, 0,0,0);
      int4v c3 = __builtin_amdgcn_mfma_i32_16x16x64_i8(a0, bq[3][0], zi, 0,0,0);
      c1 = __builtin_amdgcn_mfma_i32_16x16x64_i8(a1, bq[1][1], c1, 0,0,0);
      c3 = __builtin_amdgcn_mfma_i32_16x16x64_i8(a1, bq[3][1], c3, 0,0,0);
      float ig = __builtin_amdgcn_rcpf(1.f + __builtin_amdgcn_exp2f(
                   NL2E*__builtin_fmaf((float)c0[0], dq[0], gcur[0])));
      float gg = 1.f - 2.f*__builtin_amdgcn_rcpf(__builtin_amdgcn_exp2f(
                   P2L2E*__builtin_fmaf((float)c2[0], dq[2], gcur[2])) + 1.f);
      float igg = ig * gg;
      float fg = __builtin_amdgcn_rcpf(1.f + __builtin_amdgcn_exp2f(
                   NL2E*__builtin_fmaf((float)c1[0], dq[1], gcur[1])));
      float og = __builtin_amdgcn_rcpf(1.f + __builtin_amdgcn_exp2f(
                   NL2E*__builtin_fmaf((float)c3[0], dq[3], gcur[3])));
      cst = fg*cst + igg;
      float hn = og * (1.f - 2.f*__builtin_amdgcn_rcpf(
                   __builtin_amdgcn_exp2f(P2L2E*cst) + 1.f));
      if (quad == 0) {
        outp[(size_t)tstep*H_] = hn;
        int q = (int)rintf(hn * 127.f);
        h8_s[(s+1)&1][goff] = (unsigned char)q;
      }
      barrier_lds();
    }
  }
}

extern "C" void kernel_launch(void* const* d_in, const int* in_sizes, int n_in,
                              void* d_out, int out_size, void* d_ws, size_t ws_size,
                              hipStream_t stream)
{
  (void)in_sizes; (void)n_in; (void)out_size; (void)ws_size;
  const float* x     = (const float*)d_in[0];
  const unsigned char* xm = (const unsigned char*)d_in[1];
  const float* y     = (const float*)d_in[2];
  const unsigned char* ym = (const unsigned char*)d_in[3];
  const float* Wq_w  = (const float*)d_in[4];
  const float* Wq_b  = (const float*)d_in[5];
  const float* Wup_w = (const float*)d_in[6];
  const float* Wup_b = (const float*)d_in[7];
  const float* Wvp_b = (const float*)d_in[9];
  const float* V_w   = (const float*)d_in[10];
  const float* V_b   = (const float*)d_in[11];
  const float* Wg_w  = (const float*)d_in[12];
  const float* Wg_b  = (const float*)d_in[13];
  const float* W_ih  = (const float*)d_in[14];
  const float* W_hh  = (const float*)d_in[15];
  const float* b_ih  = (const float*)d_in[16];
  const float* b_hh  = (const float*)d_in[17];
  float* out = (float*)d_out;

  float* wsf    = (float*)d_ws;
  float* xp_ws  = wsf;                   // [3072][128]  Ex
  float* yp_ws  = xp_ws + 393216;        // [3072][128]  Ey
  float* ctp_ws = yp_ws + 393216;        // [2][3072][128] partials
  float* gx_ws  = ctp_ws + 2*393216;     // [3072][512] gate-interleaved
  float* ml_ws  = gx_ws + 1572864;       // [4][3072]   (m_i, l_i)

  proj_mfma_kernel<<<dim3(384),256,0,stream>>>(x, y, Wup_w, Wup_b, Wq_w, Wq_b, Wvp_b, xp_ws, yp_ws);
  attn_kernel<<<dim3(48,8,2),256,0,stream>>>(xp_ws, yp_ws, y, xm, ym, V_w, V_b, ctp_ws, ml_ws);
  gatefuse_kernel<<<dim3(192),256,0,stream>>>(x, ctp_ws, ml_ws, Wg_w, Wg_b, W_ih, b_ih, b_hh, gx_ws);
  lstm_kernel<<<dim3(8),512,0,stream>>>(gx_ws, W_hh, out);
}